// Round 3
// baseline (2849.016 us; speedup 1.0000x reference)
//
#include <hip/hip_runtime.h>

// ---------------------------------------------------------------------------
// AttentionLayer: q=XWq+bq, k=XWk+bk, v=XWv+bv; S=qk^T (NO 1/sqrt(d) scale);
// P=softmax(S); out=PV.   B=4, L=4096, D=768, fp32 in/out.
//
// Precision: hi/lo _Float16 split (Markidis) for X,W,Q,K -> logits ~1e-5 rel.
// P,V plain f16.  All matmuls mfma_f32_16x16x32_f16.
//
// R3: R2 work-split (S in regs per wave, P via LDS f16, 2 barriers/tile) plus
//  (a) K-split 2 across blocks -> grid 1024 -> 4 blocks/CU -> ~48% occupancy
//      (R1/R2 were grid-capped at 24%; latency-bound, MfmaUtil 9-14%).
//      Partial O~ (unnorm f32) + (m,l) per half; combine pass merges.
//      O0~ -> d_out, O1~ -> dead Xh/Xl region, ml -> dead Wth region.
//  (b) XCD pinning: slot = blockIdx.x & 7 selects (batch, K-half); all 128
//      co-resident blocks of an XCD stream the SAME 6.3 MB K-half in order
//      (R2's 1081 MB FETCH came from 4 batches' K thrashing each 4MB L2).
// ---------------------------------------------------------------------------

typedef _Float16 f16;
typedef _Float16 f16x8 __attribute__((ext_vector_type(8)));
typedef _Float16 f16x4 __attribute__((ext_vector_type(4)));
typedef float f32x4 __attribute__((ext_vector_type(4)));

#define NB 4
#define NL 4096
#define ND 768
#define NM (NB * NL)  // 16384 rows
#define KSPLIT 2
#define KHALF (NL / KSPLIT)  // 2048

__device__ __forceinline__ void split_f16(float v, f16& h, f16& l) {
    h = (f16)v;
    l = (f16)(v - (float)h);
}

// ---- convert hidden_states -> Xh, Xl (hi/lo f16), same [M][D] layout ------
__global__ __launch_bounds__(256) void k_convert_x(
    const float* __restrict__ x, f16* __restrict__ xh, f16* __restrict__ xl) {
    int i = blockIdx.x * 256 + threadIdx.x;
    float4 v = ((const float4*)x)[i];
    float vv[4] = {v.x, v.y, v.z, v.w};
    f16x4 hv, lv;
    for (int j = 0; j < 4; ++j) {
        f16 h, l; split_f16(vv[j], h, l);
        hv[j] = h; lv[j] = l;
    }
    ((f16x4*)xh)[i] = hv;
    ((f16x4*)xl)[i] = lv;
}

// ---- transpose W [k][n] -> Wt [n][k] as hi/lo f16 (3 matrices, z picks) ---
__global__ __launch_bounds__(256) void k_convert_w(
    const float* __restrict__ Wq, const float* __restrict__ Wk,
    const float* __restrict__ Wv, f16* __restrict__ wth, f16* __restrict__ wtl) {
    __shared__ float tile[32][33];
    const float* W = blockIdx.z == 0 ? Wq : (blockIdx.z == 1 ? Wk : Wv);
    f16* th = wth + blockIdx.z * ND * ND;
    f16* tl = wtl + blockIdx.z * ND * ND;
    const int k0 = blockIdx.x * 32, n0 = blockIdx.y * 32;
    const int tx = threadIdx.x & 31, ty = threadIdx.x >> 5;
    for (int r = 0; r < 4; ++r)
        tile[r * 8 + ty][tx] = W[(k0 + r * 8 + ty) * ND + n0 + tx];
    __syncthreads();
    for (int r = 0; r < 4; ++r) {
        float v = tile[tx][r * 8 + ty];
        int n = n0 + r * 8 + ty, k = k0 + tx;
        f16 h, l; split_f16(v, h, l);
        th[n * ND + k] = h;
        tl[n * ND + k] = l;
    }
}

// ---- projection GEMM: C[M,N] = X[M,K] * W[K,N] + bias, hi/lo MFMA ---------
__global__ __launch_bounds__(256, 2) void k_proj(
    const f16* __restrict__ xh, const f16* __restrict__ xl,
    const f16* __restrict__ wth, const f16* __restrict__ wtl,
    const float* __restrict__ bq, const float* __restrict__ bk,
    const float* __restrict__ bv,
    f16* __restrict__ qh, f16* __restrict__ ql,
    f16* __restrict__ kh, f16* __restrict__ kl, f16* __restrict__ vt) {
    const int z = blockIdx.z;
    const f16* wh = wth + z * ND * ND;
    const f16* wl = wtl + z * ND * ND;
    const float* bias = z == 0 ? bq : (z == 1 ? bk : bv);
    const int m0 = blockIdx.x * 128, n0 = blockIdx.y * 128;

    __shared__ f16 Ah[128 * 40], Al[128 * 40], Bh[128 * 40], Bl[128 * 40];

    const int t = threadIdx.x;
    const int lane = t & 63, quad = lane >> 4, l16 = lane & 15;
    const int wave = t >> 6, wm = wave >> 1, wn = wave & 1;

    f32x4 acc[4][4] = {};

    for (int kt = 0; kt < 24; ++kt) {
        const int k0 = kt * 32;
        __syncthreads();
        for (int i = 0; i < 2; ++i) {
            int c = i * 256 + t;
            int row = c >> 2, kc = (c & 3) * 8;
            *(uint4*)&Ah[row * 40 + kc] = *(const uint4*)&xh[(m0 + row) * ND + k0 + kc];
            *(uint4*)&Al[row * 40 + kc] = *(const uint4*)&xl[(m0 + row) * ND + k0 + kc];
            *(uint4*)&Bh[row * 40 + kc] = *(const uint4*)&wh[(n0 + row) * ND + k0 + kc];
            *(uint4*)&Bl[row * 40 + kc] = *(const uint4*)&wl[(n0 + row) * ND + k0 + kc];
        }
        __syncthreads();
        f16x8 ah[4], al[4], bh[4], bl[4];
#pragma unroll
        for (int f = 0; f < 4; ++f) {
            int m = wm * 64 + f * 16 + l16;
            ah[f] = *(const f16x8*)&Ah[m * 40 + quad * 8];
            al[f] = *(const f16x8*)&Al[m * 40 + quad * 8];
            int n = wn * 64 + f * 16 + l16;
            bh[f] = *(const f16x8*)&Bh[n * 40 + quad * 8];
            bl[f] = *(const f16x8*)&Bl[n * 40 + quad * 8];
        }
#pragma unroll
        for (int fm = 0; fm < 4; ++fm)
#pragma unroll
            for (int fn = 0; fn < 4; ++fn) {
                f32x4 c = acc[fm][fn];
                c = __builtin_amdgcn_mfma_f32_16x16x32_f16(al[fm], bh[fn], c, 0, 0, 0);
                c = __builtin_amdgcn_mfma_f32_16x16x32_f16(ah[fm], bl[fn], c, 0, 0, 0);
                c = __builtin_amdgcn_mfma_f32_16x16x32_f16(ah[fm], bh[fn], c, 0, 0, 0);
                acc[fm][fn] = c;
            }
    }
#pragma unroll
    for (int fm = 0; fm < 4; ++fm)
#pragma unroll
        for (int fn = 0; fn < 4; ++fn) {
            int col = n0 + wn * 64 + fn * 16 + l16;
            float bv_ = bias[col];
#pragma unroll
            for (int r = 0; r < 4; ++r) {
                int row = m0 + wm * 64 + fm * 16 + quad * 4 + r;
                float v = acc[fm][fn][r] + bv_;
                f16 h, l; split_f16(v, h, l);
                if (z == 0) { qh[row * ND + col] = h; ql[row * ND + col] = l; }
                else if (z == 1) { kh[row * ND + col] = h; kl[row * ND + col] = l; }
                else {
                    int b = row >> 12, pos = row & 4095;
                    vt[(b * ND + col) * NL + pos] = h;
                }
            }
        }
}

// ---- flash attention, R3: R2 structure + K-split 2 + XCD (batch,half) pin -
// blockIdx.x in [0,1024): slot=bid&7 -> batch=slot&3, half=slot>>2; qt=bid>>3.
// Each block: Q-tile 32 rows, K-range [half*2048, +2048), K-tile 128/iter.
// Writes UNNORMALIZED O~ (f32) + per-row (m,l); k_comb merges the halves.
__global__ __launch_bounds__(256, 4) void k_attn(
    const f16* __restrict__ qh, const f16* __restrict__ ql,
    const f16* __restrict__ kh, const f16* __restrict__ kl,
    const f16* __restrict__ vt, float* __restrict__ o0,
    float* __restrict__ o1, float* __restrict__ ml0, float* __restrict__ ml1) {
    const int bid = blockIdx.x;
    const int slot = bid & 7;
    const int b = slot & 3, h = slot >> 2;
    const int qt = bid >> 3;
    const int q0 = qt * 32;
    const int t = threadIdx.x, w = t >> 6, lane = t & 63;
    const int quad = lane >> 4, l16 = lane & 15;
    const int dw = w * 192;

    float* outw = h == 0 ? o0 : o1;
    float* mlw = h == 0 ? ml0 : ml1;

    __shared__ float lmax[4][32], lsum[4][32];
    __shared__ f16 Pbuf[32 * 136];

    float m_prev[2][4], l_prev[2][4];
#pragma unroll
    for (int fm = 0; fm < 2; ++fm)
#pragma unroll
        for (int r = 0; r < 4; ++r) { m_prev[fm][r] = -1e30f; l_prev[fm][r] = 0.f; }

    f32x4 oacc[2][12] = {};

    const int qbase = (b * NL + q0) * ND;

    for (int kt = 0; kt < KHALF / 128; ++kt) {
        const int p0 = h * KHALF + kt * 128;
        const int pw0 = p0 + w * 32;

        // ---- S = Q K^T for this wave's 32 positions, full D, hi/lo ----
        f32x4 sacc[2][2] = {};
#pragma unroll 3
        for (int dk = 0; dk < 24; ++dk) {
            const int d = dk * 32 + quad * 8;
            f16x8 aH[2], aL[2], bH[2], bL[2];
#pragma unroll
            for (int f = 0; f < 2; ++f) {
                const int qr = qbase + (f * 16 + l16) * ND + d;
                aH[f] = *(const f16x8*)&qh[qr];
                aL[f] = *(const f16x8*)&ql[qr];
                const int kr = (b * NL + pw0 + f * 16 + l16) * ND + d;
                bH[f] = *(const f16x8*)&kh[kr];
                bL[f] = *(const f16x8*)&kl[kr];
            }
#pragma unroll
            for (int fm = 0; fm < 2; ++fm)
#pragma unroll
                for (int fn = 0; fn < 2; ++fn) {
                    f32x4 c = sacc[fm][fn];
                    c = __builtin_amdgcn_mfma_f32_16x16x32_f16(aL[fm], bH[fn], c, 0, 0, 0);
                    c = __builtin_amdgcn_mfma_f32_16x16x32_f16(aH[fm], bL[fn], c, 0, 0, 0);
                    c = __builtin_amdgcn_mfma_f32_16x16x32_f16(aH[fm], bH[fn], c, 0, 0, 0);
                    sacc[fm][fn] = c;
                }
        }

        // ---- wave-local row max ----
        float rm[2][4];
#pragma unroll
        for (int fm = 0; fm < 2; ++fm)
#pragma unroll
            for (int r = 0; r < 4; ++r)
                rm[fm][r] = fmaxf(sacc[fm][0][r], sacc[fm][1][r]);
#pragma unroll
        for (int off = 1; off < 16; off <<= 1)
#pragma unroll
            for (int fm = 0; fm < 2; ++fm)
#pragma unroll
                for (int r = 0; r < 4; ++r)
                    rm[fm][r] = fmaxf(rm[fm][r], __shfl_xor(rm[fm][r], off, 64));
        if (l16 == 0)
#pragma unroll
            for (int fm = 0; fm < 2; ++fm)
#pragma unroll
                for (int r = 0; r < 4; ++r)
                    lmax[w][fm * 16 + quad * 4 + r] = rm[fm][r];
        __syncthreads();  // B1

        // ---- combine maxes (redundant per wave) ----
        float mn[2][4], al[2][4], ps[2][4];
#pragma unroll
        for (int fm = 0; fm < 2; ++fm)
#pragma unroll
            for (int r = 0; r < 4; ++r) {
                const int row = fm * 16 + quad * 4 + r;
                float g = fmaxf(fmaxf(lmax[0][row], lmax[1][row]),
                                fmaxf(lmax[2][row], lmax[3][row]));
                float m_old = m_prev[fm][r];
                float m_new = fmaxf(m_old, g);
                mn[fm][r] = m_new;
                al[fm][r] = __expf(m_old - m_new);
                m_prev[fm][r] = m_new;
                ps[fm][r] = 0.f;
            }
#pragma unroll
        for (int fm = 0; fm < 2; ++fm)
#pragma unroll
            for (int fn = 0; fn < 2; ++fn)
#pragma unroll
                for (int r = 0; r < 4; ++r) {
                    float p = __expf(sacc[fm][fn][r] - mn[fm][r]);
                    ps[fm][r] += p;
                    Pbuf[(fm * 16 + quad * 4 + r) * 136 + w * 32 + fn * 16 + l16] = (f16)p;
                }
#pragma unroll
        for (int off = 1; off < 16; off <<= 1)
#pragma unroll
            for (int fm = 0; fm < 2; ++fm)
#pragma unroll
                for (int r = 0; r < 4; ++r)
                    ps[fm][r] += __shfl_xor(ps[fm][r], off, 64);
        if (l16 == 0)
#pragma unroll
            for (int fm = 0; fm < 2; ++fm)
#pragma unroll
                for (int r = 0; r < 4; ++r)
                    lsum[w][fm * 16 + quad * 4 + r] = ps[fm][r];
        __syncthreads();  // B2

        // ---- l update + O rescale + PV over this wave's 192 D-cols ----
#pragma unroll
        for (int fm = 0; fm < 2; ++fm)
#pragma unroll
            for (int r = 0; r < 4; ++r) {
                const int row = fm * 16 + quad * 4 + r;
                l_prev[fm][r] = al[fm][r] * l_prev[fm][r] +
                                (lsum[0][row] + lsum[1][row] + lsum[2][row] + lsum[3][row]);
            }
#pragma unroll
        for (int fm = 0; fm < 2; ++fm)
#pragma unroll
            for (int fn = 0; fn < 12; ++fn)
#pragma unroll
                for (int r = 0; r < 4; ++r)
                    oacc[fm][fn][r] *= al[fm][r];

#pragma unroll
        for (int kk = 0; kk < 4; ++kk) {
            f16x8 pa[2];
#pragma unroll
            for (int fm = 0; fm < 2; ++fm)
                pa[fm] = *(const f16x8*)&Pbuf[(fm * 16 + l16) * 136 + kk * 32 + quad * 8];
            f16x8 vb[12];
#pragma unroll
            for (int fn = 0; fn < 12; ++fn) {
                const int dcol = dw + fn * 16 + l16;
                vb[fn] = *(const f16x8*)&vt[(b * ND + dcol) * NL + p0 + kk * 32 + quad * 8];
            }
#pragma unroll
            for (int fn = 0; fn < 12; ++fn)
#pragma unroll
                for (int fm = 0; fm < 2; ++fm)
                    oacc[fm][fn] = __builtin_amdgcn_mfma_f32_16x16x32_f16(pa[fm], vb[fn], oacc[fm][fn], 0, 0, 0);
        }
    }

    // ---- epilogue: write UNNORMALIZED O~ and (m,l) per row ----
    if (w == 0 && l16 == 0)
#pragma unroll
        for (int fm = 0; fm < 2; ++fm)
#pragma unroll
            for (int r = 0; r < 4; ++r) {
                const int row = b * NL + q0 + fm * 16 + quad * 4 + r;
                mlw[row * 2] = m_prev[fm][r];
                mlw[row * 2 + 1] = l_prev[fm][r];
            }
#pragma unroll
    for (int fm = 0; fm < 2; ++fm)
#pragma unroll
        for (int fn = 0; fn < 12; ++fn) {
            const int col = dw + fn * 16 + l16;
#pragma unroll
            for (int r = 0; r < 4; ++r) {
                const int row = b * NL + q0 + fm * 16 + quad * 4 + r;
                outw[row * ND + col] = oacc[fm][fn][r];
            }
        }
}

// ---- combine the two K-halves: out = (a0*O0 + a1*O1) / (a0*l0 + a1*l1) ----
__global__ __launch_bounds__(256) void k_comb(
    float* __restrict__ out, const float* __restrict__ o1,
    const float* __restrict__ ml0, const float* __restrict__ ml1) {
    const int i = blockIdx.x * 256 + threadIdx.x;  // float4 index; 4|768 so
    const int row = (i * 4) / ND;                  // all 4 elems share a row
    const float m0 = ml0[row * 2], l0 = ml0[row * 2 + 1];
    const float m1 = ml1[row * 2], l1 = ml1[row * 2 + 1];
    const float M = fmaxf(m0, m1);
    const float a0 = __expf(m0 - M), a1 = __expf(m1 - M);
    const float inv = 1.f / (a0 * l0 + a1 * l1);
    float4 x0 = ((const float4*)out)[i];
    float4 x1 = ((const float4*)o1)[i];
    float4 y;
    y.x = (a0 * x0.x + a1 * x1.x) * inv;
    y.y = (a0 * x0.y + a1 * x1.y) * inv;
    y.z = (a0 * x0.z + a1 * x1.z) * inv;
    y.w = (a0 * x0.w + a1 * x1.w) * inv;
    ((float4*)out)[i] = y;
}

extern "C" void kernel_launch(void* const* d_in, const int* in_sizes, int n_in,
                              void* d_out, int out_size, void* d_ws, size_t ws_size,
                              hipStream_t stream) {
    const float* hs = (const float*)d_in[0];
    const float* Wq = (const float*)d_in[1];
    const float* bq = (const float*)d_in[2];
    const float* Wk = (const float*)d_in[3];
    const float* bk = (const float*)d_in[4];
    const float* Wv = (const float*)d_in[5];
    const float* bv = (const float*)d_in[6];
    float* out = (float*)d_out;

    char* ws = (char*)d_ws;
    size_t off = 0;
    auto alloc = [&](size_t bytes) {
        void* p = ws + off;
        off += (bytes + 255) & ~(size_t)255;
        return p;
    };
    const size_t MD = (size_t)NM * ND;  // 12,582,912
    f16* Xh = (f16*)alloc(MD * 2);      // dead after k_proj -> reused as o1
    f16* Xl = (f16*)alloc(MD * 2);      //   (Xh..Xl contiguous = MD*4 bytes)
    f16* Wth = (f16*)alloc((size_t)3 * ND * ND * 2);  // dead after k_proj -> ml
    f16* Wtl = (f16*)alloc((size_t)3 * ND * ND * 2);
    f16* Qh = (f16*)alloc(MD * 2);
    f16* Ql = (f16*)alloc(MD * 2);
    f16* Kh = (f16*)alloc(MD * 2);
    f16* Kl = (f16*)alloc(MD * 2);
    f16* Vt = (f16*)alloc(MD * 2);
    (void)ws_size; (void)in_sizes; (void)n_in; (void)out_size;

    float* O1 = (float*)Xh;             // MD floats = Xh+Xl region exactly
    float* ML0 = (float*)Wth;           // 2*NM floats = 128 KB
    float* ML1 = (float*)Wth + 2 * NM;

    k_convert_x<<<dim3(MD / 1024), 256, 0, stream>>>(hs, Xh, Xl);
    k_convert_w<<<dim3(24, 24, 3), 256, 0, stream>>>(Wq, Wk, Wv, Wth, Wtl);
    k_proj<<<dim3(NM / 128, ND / 128, 3), 256, 0, stream>>>(
        Xh, Xl, Wth, Wtl, bq, bk, bv, Qh, Ql, Kh, Kl, Vt);
    k_attn<<<dim3((NL / 32) * NB * KSPLIT), 256, 0, stream>>>(
        Qh, Ql, Kh, Kl, Vt, out, O1, ML0, ML1);
    k_comb<<<dim3(MD / 1024), 256, 0, stream>>>(out, O1, ML0, ML1);
}

// Round 4
// 2424.147 us; speedup vs baseline: 1.1753x; 1.1753x over previous
//
#include <hip/hip_runtime.h>

// ---------------------------------------------------------------------------
// AttentionLayer: q=XWq+bq, k=XWk+bk, v=XWv+bv; S=qk^T (NO 1/sqrt(d) scale);
// P=softmax(S); out=PV.   B=4, L=4096, D=768, fp32 in/out.
//
// Precision: hi/lo f16 split for X,W (proj) and Q (attn). S ~= (Qh+Ql)*Kh^T
// (K-lo term dropped: adds ~0.004/logit, ~+0.01 output absmax; budget 0.114).
// P,V plain f16. All matmuls mfma_f32_16x16x32_f16.
//
// R4: Q-tile 16/block, 4 waves. oacc=48 floats/lane -> total regs ~110 ->
// fits __launch_bounds__(256,4) cap of 128 WITHOUT spilling (R3 spilled its
// 96-float oacc to scratch: VGPR_Count 64, WRITE_SIZE 3.47 GB, 2850 us).
// Grid 1024 = exactly 4 blocks/CU x 256 CU, one co-resident round, ~50% occ.
// bid%8 -> XCD pins each XCD to one batch: co-resident blocks stream the
// SAME Kh/V (3.1+6.3 MB) in order (fixes R2's measured L2 thrash).
// S-phase: wave owns 32 K-pos, S in regs. PV: wave owns 192 D-cols.
// ---------------------------------------------------------------------------

typedef _Float16 f16;
typedef _Float16 f16x8 __attribute__((ext_vector_type(8)));
typedef _Float16 f16x4 __attribute__((ext_vector_type(4)));
typedef float f32x4 __attribute__((ext_vector_type(4)));

#define NB 4
#define NL 4096
#define ND 768
#define NM (NB * NL)  // 16384 rows

__device__ __forceinline__ void split_f16(float v, f16& h, f16& l) {
    h = (f16)v;
    l = (f16)(v - (float)h);
}

// ---- convert hidden_states -> Xh, Xl (hi/lo f16), same [M][D] layout ------
__global__ __launch_bounds__(256) void k_convert_x(
    const float* __restrict__ x, f16* __restrict__ xh, f16* __restrict__ xl) {
    int i = blockIdx.x * 256 + threadIdx.x;
    float4 v = ((const float4*)x)[i];
    float vv[4] = {v.x, v.y, v.z, v.w};
    f16x4 hv, lv;
    for (int j = 0; j < 4; ++j) {
        f16 h, l; split_f16(vv[j], h, l);
        hv[j] = h; lv[j] = l;
    }
    ((f16x4*)xh)[i] = hv;
    ((f16x4*)xl)[i] = lv;
}

// ---- transpose W [k][n] -> Wt [n][k] as hi/lo f16 (3 matrices, z picks) ---
__global__ __launch_bounds__(256) void k_convert_w(
    const float* __restrict__ Wq, const float* __restrict__ Wk,
    const float* __restrict__ Wv, f16* __restrict__ wth, f16* __restrict__ wtl) {
    __shared__ float tile[32][33];
    const float* W = blockIdx.z == 0 ? Wq : (blockIdx.z == 1 ? Wk : Wv);
    f16* th = wth + blockIdx.z * ND * ND;
    f16* tl = wtl + blockIdx.z * ND * ND;
    const int k0 = blockIdx.x * 32, n0 = blockIdx.y * 32;
    const int tx = threadIdx.x & 31, ty = threadIdx.x >> 5;
    for (int r = 0; r < 4; ++r)
        tile[r * 8 + ty][tx] = W[(k0 + r * 8 + ty) * ND + n0 + tx];
    __syncthreads();
    for (int r = 0; r < 4; ++r) {
        float v = tile[tx][r * 8 + ty];
        int n = n0 + r * 8 + ty, k = k0 + tx;
        f16 h, l; split_f16(v, h, l);
        th[n * ND + k] = h;
        tl[n * ND + k] = l;
    }
}

// ---- projection GEMM: C[M,N] = X[M,K] * W[K,N] + bias, hi/lo MFMA ---------
// z=0 -> Qh/Ql; z=1 -> Kh (hi only; K-lo unused); z=2 -> Vt [b][d][pos] f16.
__global__ __launch_bounds__(256, 2) void k_proj(
    const f16* __restrict__ xh, const f16* __restrict__ xl,
    const f16* __restrict__ wth, const f16* __restrict__ wtl,
    const float* __restrict__ bq, const float* __restrict__ bk,
    const float* __restrict__ bv,
    f16* __restrict__ qh, f16* __restrict__ ql,
    f16* __restrict__ kh, f16* __restrict__ vt) {
    const int z = blockIdx.z;
    const f16* wh = wth + z * ND * ND;
    const f16* wl = wtl + z * ND * ND;
    const float* bias = z == 0 ? bq : (z == 1 ? bk : bv);
    const int m0 = blockIdx.x * 128, n0 = blockIdx.y * 128;

    __shared__ f16 Ah[128 * 40], Al[128 * 40], Bh[128 * 40], Bl[128 * 40];

    const int t = threadIdx.x;
    const int lane = t & 63, quad = lane >> 4, l16 = lane & 15;
    const int wave = t >> 6, wm = wave >> 1, wn = wave & 1;

    f32x4 acc[4][4] = {};

    for (int kt = 0; kt < 24; ++kt) {
        const int k0 = kt * 32;
        __syncthreads();
        for (int i = 0; i < 2; ++i) {
            int c = i * 256 + t;
            int row = c >> 2, kc = (c & 3) * 8;
            *(uint4*)&Ah[row * 40 + kc] = *(const uint4*)&xh[(m0 + row) * ND + k0 + kc];
            *(uint4*)&Al[row * 40 + kc] = *(const uint4*)&xl[(m0 + row) * ND + k0 + kc];
            *(uint4*)&Bh[row * 40 + kc] = *(const uint4*)&wh[(n0 + row) * ND + k0 + kc];
            *(uint4*)&Bl[row * 40 + kc] = *(const uint4*)&wl[(n0 + row) * ND + k0 + kc];
        }
        __syncthreads();
        f16x8 ah[4], al[4], bh[4], bl[4];
#pragma unroll
        for (int f = 0; f < 4; ++f) {
            int m = wm * 64 + f * 16 + l16;
            ah[f] = *(const f16x8*)&Ah[m * 40 + quad * 8];
            al[f] = *(const f16x8*)&Al[m * 40 + quad * 8];
            int n = wn * 64 + f * 16 + l16;
            bh[f] = *(const f16x8*)&Bh[n * 40 + quad * 8];
            bl[f] = *(const f16x8*)&Bl[n * 40 + quad * 8];
        }
#pragma unroll
        for (int fm = 0; fm < 4; ++fm)
#pragma unroll
            for (int fn = 0; fn < 4; ++fn) {
                f32x4 c = acc[fm][fn];
                c = __builtin_amdgcn_mfma_f32_16x16x32_f16(al[fm], bh[fn], c, 0, 0, 0);
                c = __builtin_amdgcn_mfma_f32_16x16x32_f16(ah[fm], bl[fn], c, 0, 0, 0);
                c = __builtin_amdgcn_mfma_f32_16x16x32_f16(ah[fm], bh[fn], c, 0, 0, 0);
                acc[fm][fn] = c;
            }
    }
#pragma unroll
    for (int fm = 0; fm < 4; ++fm)
#pragma unroll
        for (int fn = 0; fn < 4; ++fn) {
            int col = n0 + wn * 64 + fn * 16 + l16;
            float bv_ = bias[col];
#pragma unroll
            for (int r = 0; r < 4; ++r) {
                int row = m0 + wm * 64 + fm * 16 + quad * 4 + r;
                float v = acc[fm][fn][r] + bv_;
                f16 h, l; split_f16(v, h, l);
                if (z == 0) { qh[row * ND + col] = h; ql[row * ND + col] = l; }
                else if (z == 1) { kh[row * ND + col] = h; }
                else {
                    int b = row >> 12, pos = row & 4095;
                    vt[(b * ND + col) * NL + pos] = h;
                }
            }
        }
}

// ---- flash attention, R4: Q-tile 16, 4 waves, regs fit 4 waves/SIMD -------
// bid in [0,1024): b = bid&3 (XCD-pinned via bid%8), qt = bid>>2.
// S-phase: wave w owns K-pos [p0+32w, +32), S = (Qh+Ql)*Kh^T, sacc 8 floats.
// PV-phase: wave w owns D-cols [192w, +192), oacc 48 floats.
__global__ __launch_bounds__(256, 4) void k_attn(
    const f16* __restrict__ qh, const f16* __restrict__ ql,
    const f16* __restrict__ kh, const f16* __restrict__ vt,
    float* __restrict__ out) {
    const int bid = blockIdx.x;
    const int b = bid & 3;
    const int qt = bid >> 2;
    const int q0 = qt * 16;
    const int t = threadIdx.x, w = t >> 6, lane = t & 63;
    const int quad = lane >> 4, l16 = lane & 15;
    const int dw = w * 192;

    __shared__ float lmax[4][16], lsum[4][16];
    __shared__ f16 Pbuf[16 * 136];  // row stride 136 f16 = 272 B

    float m_prev[4], l_prev[4];
#pragma unroll
    for (int r = 0; r < 4; ++r) { m_prev[r] = -1e30f; l_prev[r] = 0.f; }

    f32x4 oacc[12] = {};

    const int qrow = (b * NL + q0 + l16) * ND;      // A-frag: m = l16
    const int kbase = (b * NL + l16) * ND;

    for (int kt = 0; kt < 32; ++kt) {
        const int p0 = kt * 128;
        const int pw0 = p0 + w * 32;

        // ---- S = (Qh+Ql) * Kh^T for this wave's 32 positions, full D ----
        f32x4 sacc[2] = {};
#pragma unroll 2
        for (int dk = 0; dk < 24; ++dk) {
            const int d = dk * 32 + quad * 8;
            f16x8 aH = *(const f16x8*)&qh[qrow + d];
            f16x8 aL = *(const f16x8*)&ql[qrow + d];
            f16x8 b0 = *(const f16x8*)&kh[kbase + pw0 * ND + d];
            f16x8 b1 = *(const f16x8*)&kh[kbase + (pw0 + 16) * ND + d];
            sacc[0] = __builtin_amdgcn_mfma_f32_16x16x32_f16(aL, b0, sacc[0], 0, 0, 0);
            sacc[0] = __builtin_amdgcn_mfma_f32_16x16x32_f16(aH, b0, sacc[0], 0, 0, 0);
            sacc[1] = __builtin_amdgcn_mfma_f32_16x16x32_f16(aL, b1, sacc[1], 0, 0, 0);
            sacc[1] = __builtin_amdgcn_mfma_f32_16x16x32_f16(aH, b1, sacc[1], 0, 0, 0);
        }

        // ---- wave-local row max (lane: rows quad*4+r, cols l16 / 16+l16) ----
        float rm[4];
#pragma unroll
        for (int r = 0; r < 4; ++r) rm[r] = fmaxf(sacc[0][r], sacc[1][r]);
#pragma unroll
        for (int off = 1; off < 16; off <<= 1)
#pragma unroll
            for (int r = 0; r < 4; ++r)
                rm[r] = fmaxf(rm[r], __shfl_xor(rm[r], off, 64));
        if (l16 == 0)
#pragma unroll
            for (int r = 0; r < 4; ++r) lmax[w][quad * 4 + r] = rm[r];
        __syncthreads();  // B1: lmax visible

        // ---- combine maxes (redundant per wave; m/l state in registers) ----
        float mn[4], alp[4], ps[4];
#pragma unroll
        for (int r = 0; r < 4; ++r) {
            const int row = quad * 4 + r;
            float g = fmaxf(fmaxf(lmax[0][row], lmax[1][row]),
                            fmaxf(lmax[2][row], lmax[3][row]));
            float m_new = fmaxf(m_prev[r], g);
            mn[r] = m_new;
            alp[r] = __expf(m_prev[r] - m_new);
            m_prev[r] = m_new;
            ps[r] = 0.f;
        }
#pragma unroll
        for (int fn = 0; fn < 2; ++fn)
#pragma unroll
            for (int r = 0; r < 4; ++r) {
                float p = __expf(sacc[fn][r] - mn[r]);
                ps[r] += p;
                Pbuf[(quad * 4 + r) * 136 + w * 32 + fn * 16 + l16] = (f16)p;
            }
#pragma unroll
        for (int off = 1; off < 16; off <<= 1)
#pragma unroll
            for (int r = 0; r < 4; ++r) ps[r] += __shfl_xor(ps[r], off, 64);
        if (l16 == 0)
#pragma unroll
            for (int r = 0; r < 4; ++r) lsum[w][quad * 4 + r] = ps[r];
        __syncthreads();  // B2: Pbuf + lsum visible

        // ---- l update + O rescale + PV over this wave's 192 D-cols ----
#pragma unroll
        for (int r = 0; r < 4; ++r) {
            const int row = quad * 4 + r;
            l_prev[r] = alp[r] * l_prev[r] +
                        (lsum[0][row] + lsum[1][row] + lsum[2][row] + lsum[3][row]);
        }
#pragma unroll
        for (int fn = 0; fn < 12; ++fn)
#pragma unroll
            for (int r = 0; r < 4; ++r) oacc[fn][r] *= alp[r];

#pragma unroll
        for (int kk = 0; kk < 4; ++kk) {
            f16x8 pa = *(const f16x8*)&Pbuf[l16 * 136 + kk * 32 + quad * 8];
            f16x8 vb[12];
#pragma unroll
            for (int fn = 0; fn < 12; ++fn)
                vb[fn] = *(const f16x8*)&vt[(b * ND + dw + fn * 16 + l16) * NL +
                                            p0 + kk * 32 + quad * 8];
#pragma unroll
            for (int fn = 0; fn < 12; ++fn)
                oacc[fn] = __builtin_amdgcn_mfma_f32_16x16x32_f16(pa, vb[fn], oacc[fn], 0, 0, 0);
        }
        // next tile's lmax/Pbuf writes are fenced by B1/B2
    }

    // ---- epilogue: out = O / l (normalized directly; no combine pass) ----
    float linv[4];
#pragma unroll
    for (int r = 0; r < 4; ++r) linv[r] = 1.f / l_prev[r];
#pragma unroll
    for (int fn = 0; fn < 12; ++fn) {
        const int col = dw + fn * 16 + l16;
#pragma unroll
        for (int r = 0; r < 4; ++r) {
            const int row = b * NL + q0 + quad * 4 + r;
            out[row * ND + col] = oacc[fn][r] * linv[r];
        }
    }
}

extern "C" void kernel_launch(void* const* d_in, const int* in_sizes, int n_in,
                              void* d_out, int out_size, void* d_ws, size_t ws_size,
                              hipStream_t stream) {
    const float* hs = (const float*)d_in[0];
    const float* Wq = (const float*)d_in[1];
    const float* bq = (const float*)d_in[2];
    const float* Wk = (const float*)d_in[3];
    const float* bk = (const float*)d_in[4];
    const float* Wv = (const float*)d_in[5];
    const float* bv = (const float*)d_in[6];
    float* out = (float*)d_out;

    char* ws = (char*)d_ws;
    size_t off = 0;
    auto alloc = [&](size_t bytes) {
        void* p = ws + off;
        off += (bytes + 255) & ~(size_t)255;
        return p;
    };
    const size_t MD = (size_t)NM * ND;  // 12,582,912
    f16* Xh = (f16*)alloc(MD * 2);
    f16* Xl = (f16*)alloc(MD * 2);
    f16* Wth = (f16*)alloc((size_t)3 * ND * ND * 2);
    f16* Wtl = (f16*)alloc((size_t)3 * ND * ND * 2);
    f16* Qh = (f16*)alloc(MD * 2);
    f16* Ql = (f16*)alloc(MD * 2);
    f16* Kh = (f16*)alloc(MD * 2);
    f16* Vt = (f16*)alloc(MD * 2);
    (void)ws_size; (void)in_sizes; (void)n_in; (void)out_size;

    k_convert_x<<<dim3(MD / 1024), 256, 0, stream>>>(hs, Xh, Xl);
    k_convert_w<<<dim3(24, 24, 3), 256, 0, stream>>>(Wq, Wk, Wv, Wth, Wtl);
    k_proj<<<dim3(NM / 128, ND / 128, 3), 256, 0, stream>>>(
        Xh, Xl, Wth, Wtl, bq, bk, bv, Qh, Ql, Kh, Vt);
    k_attn<<<dim3((NL / 16) * NB), 256, 0, stream>>>(Qh, Ql, Kh, Vt, out);
}

// Round 5
// 2333.491 us; speedup vs baseline: 1.2209x; 1.0388x over previous
//
#include <hip/hip_runtime.h>

// ---------------------------------------------------------------------------
// AttentionLayer: q=XWq+bq, k=XWk+bk, v=XWv+bv; S=qk^T (NO 1/sqrt(d) scale);
// P=softmax(S); out=PV.   B=4, L=4096, D=768, fp32 in/out.
//
// Precision: hi/lo f16 split for X,W (proj) and Q (attn). S ~= (Qh+Ql)*Kh^T
// (K-lo dropped: ~0.004/logit -> absmax 0.035, budget 0.114). P,V plain f16.
//
// R5: fix the R3/R4 spill. Empirical: __launch_bounds__(256,4) makes the
// allocator target 64 arch-VGPRs -> oacc/vb spill to scratch (R3: 3.5 GB
// writes; R4: 465 MB writes, FETCH 1.5 GB, VGPR_Count=64 both times).
// (256,2) gave 120 regs + NO spill on the larger R2 kernel. So: use (256,2),
// shrink PV peak pressure (vb in chunks of 4), and let actual usage <=128
// give 4 waves/EU naturally (HW occupancy steps at vgpr 64/128/256 - m69).
// Grid 1024 = 4 blocks/CU; bid%8 pins each XCD to one batch's K/V stream.
// ---------------------------------------------------------------------------

typedef _Float16 f16;
typedef _Float16 f16x8 __attribute__((ext_vector_type(8)));
typedef _Float16 f16x4 __attribute__((ext_vector_type(4)));
typedef float f32x4 __attribute__((ext_vector_type(4)));

#define NB 4
#define NL 4096
#define ND 768
#define NM (NB * NL)  // 16384 rows

__device__ __forceinline__ void split_f16(float v, f16& h, f16& l) {
    h = (f16)v;
    l = (f16)(v - (float)h);
}

// ---- convert hidden_states -> Xh, Xl (hi/lo f16), same [M][D] layout ------
__global__ __launch_bounds__(256) void k_convert_x(
    const float* __restrict__ x, f16* __restrict__ xh, f16* __restrict__ xl) {
    int i = blockIdx.x * 256 + threadIdx.x;
    float4 v = ((const float4*)x)[i];
    float vv[4] = {v.x, v.y, v.z, v.w};
    f16x4 hv, lv;
    for (int j = 0; j < 4; ++j) {
        f16 h, l; split_f16(vv[j], h, l);
        hv[j] = h; lv[j] = l;
    }
    ((f16x4*)xh)[i] = hv;
    ((f16x4*)xl)[i] = lv;
}

// ---- transpose W [k][n] -> Wt [n][k] as hi/lo f16 (3 matrices, z picks) ---
__global__ __launch_bounds__(256) void k_convert_w(
    const float* __restrict__ Wq, const float* __restrict__ Wk,
    const float* __restrict__ Wv, f16* __restrict__ wth, f16* __restrict__ wtl) {
    __shared__ float tile[32][33];
    const float* W = blockIdx.z == 0 ? Wq : (blockIdx.z == 1 ? Wk : Wv);
    f16* th = wth + blockIdx.z * ND * ND;
    f16* tl = wtl + blockIdx.z * ND * ND;
    const int k0 = blockIdx.x * 32, n0 = blockIdx.y * 32;
    const int tx = threadIdx.x & 31, ty = threadIdx.x >> 5;
    for (int r = 0; r < 4; ++r)
        tile[r * 8 + ty][tx] = W[(k0 + r * 8 + ty) * ND + n0 + tx];
    __syncthreads();
    for (int r = 0; r < 4; ++r) {
        float v = tile[tx][r * 8 + ty];
        int n = n0 + r * 8 + ty, k = k0 + tx;
        f16 h, l; split_f16(v, h, l);
        th[n * ND + k] = h;
        tl[n * ND + k] = l;
    }
}

// ---- projection GEMM: C[M,N] = X[M,K] * W[K,N] + bias, hi/lo MFMA ---------
// z=0 -> Qh/Ql; z=1 -> Kh (hi only); z=2 -> Vt [b][d][pos] f16.
__global__ __launch_bounds__(256, 2) void k_proj(
    const f16* __restrict__ xh, const f16* __restrict__ xl,
    const f16* __restrict__ wth, const f16* __restrict__ wtl,
    const float* __restrict__ bq, const float* __restrict__ bk,
    const float* __restrict__ bv,
    f16* __restrict__ qh, f16* __restrict__ ql,
    f16* __restrict__ kh, f16* __restrict__ vt) {
    const int z = blockIdx.z;
    const f16* wh = wth + z * ND * ND;
    const f16* wl = wtl + z * ND * ND;
    const float* bias = z == 0 ? bq : (z == 1 ? bk : bv);
    const int m0 = blockIdx.x * 128, n0 = blockIdx.y * 128;

    __shared__ f16 Ah[128 * 40], Al[128 * 40], Bh[128 * 40], Bl[128 * 40];

    const int t = threadIdx.x;
    const int lane = t & 63, quad = lane >> 4, l16 = lane & 15;
    const int wave = t >> 6, wm = wave >> 1, wn = wave & 1;

    f32x4 acc[4][4] = {};

    for (int kt = 0; kt < 24; ++kt) {
        const int k0 = kt * 32;
        __syncthreads();
        for (int i = 0; i < 2; ++i) {
            int c = i * 256 + t;
            int row = c >> 2, kc = (c & 3) * 8;
            *(uint4*)&Ah[row * 40 + kc] = *(const uint4*)&xh[(m0 + row) * ND + k0 + kc];
            *(uint4*)&Al[row * 40 + kc] = *(const uint4*)&xl[(m0 + row) * ND + k0 + kc];
            *(uint4*)&Bh[row * 40 + kc] = *(const uint4*)&wh[(n0 + row) * ND + k0 + kc];
            *(uint4*)&Bl[row * 40 + kc] = *(const uint4*)&wl[(n0 + row) * ND + k0 + kc];
        }
        __syncthreads();
        f16x8 ah[4], al[4], bh[4], bl[4];
#pragma unroll
        for (int f = 0; f < 4; ++f) {
            int m = wm * 64 + f * 16 + l16;
            ah[f] = *(const f16x8*)&Ah[m * 40 + quad * 8];
            al[f] = *(const f16x8*)&Al[m * 40 + quad * 8];
            int n = wn * 64 + f * 16 + l16;
            bh[f] = *(const f16x8*)&Bh[n * 40 + quad * 8];
            bl[f] = *(const f16x8*)&Bl[n * 40 + quad * 8];
        }
#pragma unroll
        for (int fm = 0; fm < 4; ++fm)
#pragma unroll
            for (int fn = 0; fn < 4; ++fn) {
                f32x4 c = acc[fm][fn];
                c = __builtin_amdgcn_mfma_f32_16x16x32_f16(al[fm], bh[fn], c, 0, 0, 0);
                c = __builtin_amdgcn_mfma_f32_16x16x32_f16(ah[fm], bl[fn], c, 0, 0, 0);
                c = __builtin_amdgcn_mfma_f32_16x16x32_f16(ah[fm], bh[fn], c, 0, 0, 0);
                acc[fm][fn] = c;
            }
    }
#pragma unroll
    for (int fm = 0; fm < 4; ++fm)
#pragma unroll
        for (int fn = 0; fn < 4; ++fn) {
            int col = n0 + wn * 64 + fn * 16 + l16;
            float bv_ = bias[col];
#pragma unroll
            for (int r = 0; r < 4; ++r) {
                int row = m0 + wm * 64 + fm * 16 + quad * 4 + r;
                float v = acc[fm][fn][r] + bv_;
                f16 h, l; split_f16(v, h, l);
                if (z == 0) { qh[row * ND + col] = h; ql[row * ND + col] = l; }
                else if (z == 1) { kh[row * ND + col] = h; }
                else {
                    int b = row >> 12, pos = row & 4095;
                    vt[(b * ND + col) * NL + pos] = h;
                }
            }
        }
}

// ---- flash attention, R5: Q-tile 16, 4 waves, (256,2), low PV pressure ----
// bid in [0,1024): b = bid&3 (XCD-pinned via bid%8), qt = bid>>2.
// S-phase: wave w owns K-pos [p0+32w, +32), S = (Qh+Ql)*Kh^T, sacc 8 floats.
// PV-phase: wave w owns D-cols [192w, +192), oacc 48 floats, vb in chunks of 4.
__global__ __launch_bounds__(256, 2) void k_attn(
    const f16* __restrict__ qh, const f16* __restrict__ ql,
    const f16* __restrict__ kh, const f16* __restrict__ vt,
    float* __restrict__ out) {
    const int bid = blockIdx.x;
    const int b = bid & 3;
    const int qt = bid >> 2;
    const int q0 = qt * 16;
    const int t = threadIdx.x, w = t >> 6, lane = t & 63;
    const int quad = lane >> 4, l16 = lane & 15;
    const int dw = w * 192;

    __shared__ float lmax[4][16], lsum[4][16];
    __shared__ f16 Pbuf[16 * 136];  // row stride 136 f16 = 272 B

    float m_prev[4], l_prev[4];
#pragma unroll
    for (int r = 0; r < 4; ++r) { m_prev[r] = -1e30f; l_prev[r] = 0.f; }

    f32x4 oacc[12] = {};

    const int qrow = (b * NL + q0 + l16) * ND;      // A-frag: m = l16
    const int kbase = (b * NL + l16) * ND;

    for (int kt = 0; kt < 32; ++kt) {
        const int p0 = kt * 128;
        const int pw0 = p0 + w * 32;

        // ---- S = (Qh+Ql) * Kh^T for this wave's 32 positions, full D ----
        f32x4 sacc[2] = {};
#pragma unroll 2
        for (int dk = 0; dk < 24; ++dk) {
            const int d = dk * 32 + quad * 8;
            f16x8 aH = *(const f16x8*)&qh[qrow + d];
            f16x8 aL = *(const f16x8*)&ql[qrow + d];
            f16x8 b0 = *(const f16x8*)&kh[kbase + pw0 * ND + d];
            f16x8 b1 = *(const f16x8*)&kh[kbase + (pw0 + 16) * ND + d];
            sacc[0] = __builtin_amdgcn_mfma_f32_16x16x32_f16(aL, b0, sacc[0], 0, 0, 0);
            sacc[0] = __builtin_amdgcn_mfma_f32_16x16x32_f16(aH, b0, sacc[0], 0, 0, 0);
            sacc[1] = __builtin_amdgcn_mfma_f32_16x16x32_f16(aL, b1, sacc[1], 0, 0, 0);
            sacc[1] = __builtin_amdgcn_mfma_f32_16x16x32_f16(aH, b1, sacc[1], 0, 0, 0);
        }

        // ---- wave-local row max (rows quad*4+r, cols l16 / 16+l16) ----
        float rm[4];
#pragma unroll
        for (int r = 0; r < 4; ++r) rm[r] = fmaxf(sacc[0][r], sacc[1][r]);
#pragma unroll
        for (int off = 1; off < 16; off <<= 1)
#pragma unroll
            for (int r = 0; r < 4; ++r)
                rm[r] = fmaxf(rm[r], __shfl_xor(rm[r], off, 64));
        if (l16 == 0)
#pragma unroll
            for (int r = 0; r < 4; ++r) lmax[w][quad * 4 + r] = rm[r];
        __syncthreads();  // B1: lmax visible

        // ---- combine maxes (redundant per wave; m/l state in registers) ----
        float mn[4], alp[4], ps[4];
#pragma unroll
        for (int r = 0; r < 4; ++r) {
            const int row = quad * 4 + r;
            float g = fmaxf(fmaxf(lmax[0][row], lmax[1][row]),
                            fmaxf(lmax[2][row], lmax[3][row]));
            float m_new = fmaxf(m_prev[r], g);
            mn[r] = m_new;
            alp[r] = __expf(m_prev[r] - m_new);
            m_prev[r] = m_new;
            ps[r] = 0.f;
        }
#pragma unroll
        for (int fn = 0; fn < 2; ++fn)
#pragma unroll
            for (int r = 0; r < 4; ++r) {
                float p = __expf(sacc[fn][r] - mn[r]);
                ps[r] += p;
                Pbuf[(quad * 4 + r) * 136 + w * 32 + fn * 16 + l16] = (f16)p;
            }
#pragma unroll
        for (int off = 1; off < 16; off <<= 1)
#pragma unroll
            for (int r = 0; r < 4; ++r) ps[r] += __shfl_xor(ps[r], off, 64);
        if (l16 == 0)
#pragma unroll
            for (int r = 0; r < 4; ++r) lsum[w][quad * 4 + r] = ps[r];
        __syncthreads();  // B2: Pbuf + lsum visible

        // ---- l update + O rescale + PV over this wave's 192 D-cols ----
#pragma unroll
        for (int r = 0; r < 4; ++r) {
            const int row = quad * 4 + r;
            l_prev[r] = alp[r] * l_prev[r] +
                        (lsum[0][row] + lsum[1][row] + lsum[2][row] + lsum[3][row]);
        }
#pragma unroll
        for (int fn = 0; fn < 12; ++fn)
#pragma unroll
            for (int r = 0; r < 4; ++r) oacc[fn][r] *= alp[r];

        // vb in chunks of 4 to keep peak arch-VGPR pressure low (spill fix)
#pragma unroll
        for (int kk = 0; kk < 4; ++kk) {
            f16x8 pa = *(const f16x8*)&Pbuf[l16 * 136 + kk * 32 + quad * 8];
#pragma unroll
            for (int g = 0; g < 3; ++g) {
                f16x8 vb[4];
#pragma unroll
                for (int j = 0; j < 4; ++j)
                    vb[j] = *(const f16x8*)&vt[(b * ND + dw + (g * 4 + j) * 16 + l16) * NL +
                                               p0 + kk * 32 + quad * 8];
#pragma unroll
                for (int j = 0; j < 4; ++j)
                    oacc[g * 4 + j] = __builtin_amdgcn_mfma_f32_16x16x32_f16(
                        pa, vb[j], oacc[g * 4 + j], 0, 0, 0);
            }
        }
        // next tile's lmax/Pbuf writes are fenced by B1/B2
    }

    // ---- epilogue: out = O / l ----
    float linv[4];
#pragma unroll
    for (int r = 0; r < 4; ++r) linv[r] = 1.f / l_prev[r];
#pragma unroll
    for (int fn = 0; fn < 12; ++fn) {
        const int col = dw + fn * 16 + l16;
#pragma unroll
        for (int r = 0; r < 4; ++r) {
            const int row = b * NL + q0 + quad * 4 + r;
            out[row * ND + col] = oacc[fn][r] * linv[r];
        }
    }
}

extern "C" void kernel_launch(void* const* d_in, const int* in_sizes, int n_in,
                              void* d_out, int out_size, void* d_ws, size_t ws_size,
                              hipStream_t stream) {
    const float* hs = (const float*)d_in[0];
    const float* Wq = (const float*)d_in[1];
    const float* bq = (const float*)d_in[2];
    const float* Wk = (const float*)d_in[3];
    const float* bk = (const float*)d_in[4];
    const float* Wv = (const float*)d_in[5];
    const float* bv = (const float*)d_in[6];
    float* out = (float*)d_out;

    char* ws = (char*)d_ws;
    size_t off = 0;
    auto alloc = [&](size_t bytes) {
        void* p = ws + off;
        off += (bytes + 255) & ~(size_t)255;
        return p;
    };
    const size_t MD = (size_t)NM * ND;  // 12,582,912
    f16* Xh = (f16*)alloc(MD * 2);
    f16* Xl = (f16*)alloc(MD * 2);
    f16* Wth = (f16*)alloc((size_t)3 * ND * ND * 2);
    f16* Wtl = (f16*)alloc((size_t)3 * ND * ND * 2);
    f16* Qh = (f16*)alloc(MD * 2);
    f16* Ql = (f16*)alloc(MD * 2);
    f16* Kh = (f16*)alloc(MD * 2);
    f16* Vt = (f16*)alloc(MD * 2);
    (void)ws_size; (void)in_sizes; (void)n_in; (void)out_size;

    k_convert_x<<<dim3(MD / 1024), 256, 0, stream>>>(hs, Xh, Xl);
    k_convert_w<<<dim3(24, 24, 3), 256, 0, stream>>>(Wq, Wk, Wv, Wth, Wtl);
    k_proj<<<dim3(NM / 128, ND / 128, 3), 256, 0, stream>>>(
        Xh, Xl, Wth, Wtl, bq, bk, bv, Qh, Ql, Kh, Vt);
    k_attn<<<dim3((NL / 16) * NB), 256, 0, stream>>>(Qh, Ql, Kh, Vt, out);
}